// Round 4
// baseline (519.060 us; speedup 1.0000x reference)
//
#include <hip/hip_runtime.h>
#include <math.h>

#define Nn 4096
#define Ee 32768
#define Bb 64
#define FINc 128
#define Dd 64
#define SIGf 0.15f
#define LAMf 0.01f
#define EPSf 1e-5f

typedef __attribute__((ext_vector_type(8))) short bf16x8;
typedef __attribute__((ext_vector_type(4))) float f32x4;

__device__ inline short f2bf(float f) {
  union { float f; unsigned u; } v; v.f = f;
  unsigned r = v.u + 0x7fffu + ((v.u >> 16) & 1u);
  return (short)(r >> 16);
}
__device__ inline bf16x8 pack8v(f32x4 a, f32x4 b) {
  bf16x8 r;
  r[0]=f2bf(a.x); r[1]=f2bf(a.y); r[2]=f2bf(a.z); r[3]=f2bf(a.w);
  r[4]=f2bf(b.x); r[5]=f2bf(b.y); r[6]=f2bf(b.z); r[7]=f2bf(b.w);
  return r;
}
__device__ inline float sigm(float x) { return 1.f / (1.f + expf(-x)); }

// ================= setup: w2 transpose + packs + count + pcnt + tkl =================
// blocks 0..191: w2T transpose  | 192..199: small packs | 200..327: count | 328: tkl
__global__ __launch_bounds__(256) void k_setup(
    const float* __restrict__ w1, const float* __restrict__ w2,
    const float* __restrict__ b2, const float* __restrict__ rootw,
    const float* __restrict__ gwih, const float* __restrict__ gwhh,
    const float* __restrict__ preW,
    const float* __restrict__ preb, const float* __restrict__ postW,
    const float* __restrict__ postb, const float* __restrict__ outW,
    const float* __restrict__ outb,
    const int* __restrict__ dst, const int* __restrict__ batch,
    short* __restrict__ w1T, short* __restrict__ b2T,
    short* __restrict__ w2T, short* __restrict__ rootwT,
    short* __restrict__ gwihB, short* __restrict__ gwhhB,
    short* __restrict__ preWT,
    float* __restrict__ cnt, float* __restrict__ pcnt, float* __restrict__ y) {
  const int b = blockIdx.x, tid = threadIdx.x;
  if (b < 192) {
    __shared__ float tile[64*65];
    const int l = b >> 6, h = b & 63;
    const float* srcp = w2 + (size_t)(l*64 + h)*4096;
    #pragma unroll
    for (int it = 0; it < 16; ++it) {
      int j = tid + 256*it;                 // j = f*64 + o, coalesced read
      tile[(j >> 6)*65 + (j & 63)] = srcp[j];
    }
    __syncthreads();
    short* dstp = w2T + (size_t)(l*64 + h)*4096;
    #pragma unroll
    for (int it = 0; it < 16; ++it) {
      int j = tid + 256*it;                 // j = o*64 + f, coalesced write
      int o = j >> 6, f = j & 63;
      dstp[j] = f2bf(tile[f*65 + o]);
    }
  } else if (b < 200) {
    int base = (b - 192)*256 + tid;         // 0..2047
    for (int idx = base; idx < 12288; idx += 2048) {
      int l = idx >> 12, r = idx & 4095;
      int f = r & 63, c = r >> 6;
      w1T[idx]    = f2bf(w1[l*4096 + f*64 + c]);
      b2T[idx]    = f2bf(b2[l*4096 + f*64 + c]);
      rootwT[idx] = f2bf(rootw[l*4096 + f*64 + c]);
    }
    for (int idx = base; idx < 36864; idx += 2048) {
      gwihB[idx] = f2bf(gwih[idx]);
      gwhhB[idx] = f2bf(gwhh[idx]);
    }
    for (int idx = base; idx < 8192; idx += 2048) {
      int k = idx & 127, d = idx >> 7;
      preWT[idx] = f2bf(preW[k*64 + d]);
    }
  } else if (b < 328) {
    int e = (b - 200)*256 + tid;
    atomicAdd(&cnt[dst[e]], 1.0f);
    if (e < Nn) atomicAdd(&pcnt[batch[e]], 1.0f);
  } else {
    const float logc = logf(SIGf * sqrtf(6.28318530717958647692f));
    const float c2 = 0.5f / (SIGf * SIGf);
    float acc = 0.f;
    for (int i = tid; i < FINc*Dd; i += 256) { float w = preW[i];  acc += c2*w*w + logc; }
    for (int i = tid; i < Dd; i += 256)      { float w = preb[i];  acc += c2*w*w + logc; }
    for (int i = tid; i < Dd*Dd; i += 256)   { float w = postW[i]; acc += c2*w*w + logc; }
    for (int i = tid; i < Dd; i += 256)      { float w = postb[i]; acc += c2*w*w + logc; }
    for (int i = tid; i < Dd; i += 256)      { float w = outW[i];  acc += c2*w*w + logc; }
    if (tid == 0)                            { float w = outb[0];  acc += c2*w*w + logc; }
    __shared__ float red[256];
    red[tid] = acc; __syncthreads();
    for (int s = 128; s > 0; s >>= 1) { if (tid < s) red[tid] += red[tid+s]; __syncthreads(); }
    if (tid == 0) y[Bb] = red[0];
  }
}

// ---------------- pre FC + relu via MFMA ----------------
__global__ __launch_bounds__(256) void k_pre(const float* __restrict__ x,
                                             const short* __restrict__ preWT,
                                             const float* __restrict__ preb,
                                             float* __restrict__ out, float* __restrict__ h) {
  const int tid = threadIdx.x, lane = tid & 63, wave = tid >> 6;
  const int m15 = lane & 15, kq = lane >> 4;
  const int nb = blockIdx.x * 32;
  const f32x4 zero4 = {0.f,0.f,0.f,0.f};
  const int d = wave*16 + m15;
  bf16x8 bfr[4];
  #pragma unroll
  for (int c = 0; c < 4; ++c)
    bfr[c] = *(const bf16x8*)(preWT + d*128 + c*32 + kq*8);
  #pragma unroll
  for (int t = 0; t < 2; ++t) {
    const float* xp = x + (size_t)(nb + t*16 + m15)*128 + kq*8;
    f32x4 p = zero4;
    #pragma unroll
    for (int c = 0; c < 4; ++c) {
      bf16x8 a = pack8v(*(const f32x4*)(xp + c*32), *(const f32x4*)(xp + c*32 + 4));
      p = __builtin_amdgcn_mfma_f32_16x16x32_bf16(a, bfr[c], p, 0, 0, 0);
    }
    float bv = preb[d];
    #pragma unroll
    for (int r = 0; r < 4; ++r) {
      int node = nb + t*16 + kq*4 + r;
      float v = fmaxf(p[r] + bv, 0.f);
      out[node*64 + d] = v;
      h[node*64 + d] = v;
    }
  }
}

// ====== fused edge-MLP + bilinear message GEMM, 8 waves, h split across wave pairs ======
__global__ __launch_bounds__(512, 4) void k_msg(
    const float* __restrict__ out, const float* __restrict__ edge_attr,
    const short* __restrict__ w1T, const float* __restrict__ b1,
    const short* __restrict__ w2T, const short* __restrict__ b2T,
    const int* __restrict__ src, const int* __restrict__ dst,
    float* __restrict__ agg) {
  __shared__ __align__(16) float hidT[64*68];   // [h][e] stride 68; reused as reduce buf
  __shared__ int srcv[64];
  __shared__ int dstv[64];

  const int tid  = threadIdx.x;
  const int lane = tid & 63;
  const int w    = tid >> 6;      // 0..7
  const int ow   = w & 3;         // o-column group
  const int hh   = w >> 2;        // h-half (0: h 0..31, 1: h 32..63 + b2)
  const int m15  = lane & 15;
  const int kq   = lane >> 4;
  const int ebase = blockIdx.x * 64;

  if (tid < 64) { srcv[tid] = src[ebase + tid]; dstv[tid] = dst[ebase + tid]; }
  __syncthreads();

  const f32x4 zero4 = {0.f, 0.f, 0.f, 0.f};

  // ---- A-fragments: s = out[src] (all 4 row-tiles, kept in regs) ----
  bf16x8 sfrag[4][2];
  #pragma unroll
  for (int t = 0; t < 4; ++t) {
    int node = srcv[t*16 + m15];
    const float* sp = out + (size_t)node*64 + kq*8;
    #pragma unroll
    for (int ks = 0; ks < 2; ++ks)
      sfrag[t][ks] = pack8v(*(const f32x4*)(sp + ks*32), *(const f32x4*)(sp + ks*32 + 4));
  }

  // ---- hid = relu(ea @ w1 + b1): wave handles h-col ow*16+m15, t in {hh*2, hh*2+1} ----
  {
    const short* wp = w1T + (ow*16 + m15)*64 + kq*8;
    bf16x8 bw0 = *(const bf16x8*)(wp);
    bf16x8 bw1 = *(const bf16x8*)(wp + 32);
    float b1v = b1[ow*16 + m15];
    #pragma unroll
    for (int tt = 0; tt < 2; ++tt) {
      int t = hh*2 + tt;
      const float* ep = edge_attr + (size_t)(ebase + t*16 + m15)*64 + kq*8;
      bf16x8 a0 = pack8v(*(const f32x4*)(ep),      *(const f32x4*)(ep + 4));
      bf16x8 a1 = pack8v(*(const f32x4*)(ep + 32), *(const f32x4*)(ep + 36));
      f32x4 p = __builtin_amdgcn_mfma_f32_16x16x32_bf16(a0, bw0, zero4, 0, 0, 0);
      p = __builtin_amdgcn_mfma_f32_16x16x32_bf16(a1, bw1, p, 0, 0, 0);
      f32x4 v;
      v.x = fmaxf(p.x + b1v, 0.f); v.y = fmaxf(p.y + b1v, 0.f);
      v.z = fmaxf(p.z + b1v, 0.f); v.w = fmaxf(p.w + b1v, 0.f);
      *(f32x4*)(hidT + (ow*16 + m15)*68 + t*16 + kq*4) = v;
    }
  }
  __syncthreads();

  // ---- K-loop: 32 h-chunks per wave, prefetch depth 2 ----
  f32x4 acc[4] = {zero4, zero4, zero4, zero4};
  const short* base = w2T + (ow*16 + m15)*64 + kq*8;
  const short* b2p  = b2T + (ow*16 + m15)*64 + kq*8;
  const short* p0 = base + (size_t)(hh*32)*4096;
  const short* p1 = base + (size_t)(hh*32 + 1)*4096;
  bf16x8 c00 = *(const bf16x8*)p0, c01 = *(const bf16x8*)(p0 + 32);
  bf16x8 c10 = *(const bf16x8*)p1, c11 = *(const bf16x8*)(p1 + 32);
  for (int c = 0; c < 32; ++c) {
    const short* pn = (c < 30) ? base + (size_t)(hh*32 + c + 2)*4096 : b2p;
    bf16x8 n0 = *(const bf16x8*)pn, n1 = *(const bf16x8*)(pn + 32);
    #pragma unroll
    for (int t = 0; t < 4; ++t) {
      f32x4 p = __builtin_amdgcn_mfma_f32_16x16x32_bf16(sfrag[t][0], c00, zero4, 0, 0, 0);
      p = __builtin_amdgcn_mfma_f32_16x16x32_bf16(sfrag[t][1], c01, p, 0, 0, 0);
      f32x4 hv = *(const f32x4*)(hidT + (hh*32 + c)*68 + t*16 + kq*4);
      acc[t].x += hv.x * p.x; acc[t].y += hv.y * p.y;
      acc[t].z += hv.z * p.z; acc[t].w += hv.w * p.w;
    }
    c00 = c10; c01 = c11; c10 = n0; c11 = n1;
  }
  if (hh) {  // b2 chunk, scale 1 (sum_f s[e,f] * b2[f,o])
    #pragma unroll
    for (int t = 0; t < 4; ++t) {
      f32x4 p = __builtin_amdgcn_mfma_f32_16x16x32_bf16(sfrag[t][0], c00, zero4, 0, 0, 0);
      p = __builtin_amdgcn_mfma_f32_16x16x32_bf16(sfrag[t][1], c01, p, 0, 0, 0);
      acc[t].x += p.x; acc[t].y += p.y; acc[t].z += p.z; acc[t].w += p.w;
    }
  }

  // ---- reduce the two h-halves via LDS (reuse hidT), then scatter ----
  __syncthreads();   // all hidT reads done
  if (hh) {
    #pragma unroll
    for (int t = 0; t < 4; ++t)
      *(f32x4*)(hidT + (ow*64 + lane)*17 + t*4) = acc[t];
  }
  __syncthreads();
  if (!hh) {
    #pragma unroll
    for (int t = 0; t < 4; ++t) {
      f32x4 o4 = *(const f32x4*)(hidT + (ow*64 + lane)*17 + t*4);
      acc[t].x += o4.x; acc[t].y += o4.y; acc[t].z += o4.z; acc[t].w += o4.w;
    }
    const int o = ow*16 + m15;
    #pragma unroll
    for (int t = 0; t < 4; ++t) {
      #pragma unroll
      for (int r = 0; r < 4; ++r) {
        int e = t*16 + kq*4 + r;
        atomicAdd(&agg[(size_t)dstv[e]*64 + o], acc[t][r]);
      }
    }
  }
}

// ---------------- fused: m = agg/cnt + out@rootw + rootb ; softmax ; BN stats ----------------
__global__ __launch_bounds__(256) void k_m_fused(
    const float* __restrict__ agg_c, const float* __restrict__ cnt,
    const float* __restrict__ out, const short* __restrict__ rootwT,
    const float* __restrict__ rootb, const float* __restrict__ gnlin,
    float* __restrict__ m, float* __restrict__ sbuf, float* __restrict__ stats,
    float* __restrict__ agg_z) {
  __shared__ float msh[64*65];
  __shared__ float lgsh[64*12];
  __shared__ float ssh[64*16];
  const int tid = threadIdx.x, lane = tid & 63, wave = tid >> 6;
  const int m15 = lane & 15, kq = lane >> 4;
  const int nb = blockIdx.x * 64;
  const f32x4 zero4 = {0.f,0.f,0.f,0.f};
  const int d = wave*16 + m15;

  bf16x8 b0 = *(const bf16x8*)(rootwT + d*64 + kq*8);
  bf16x8 b1 = *(const bf16x8*)(rootwT + d*64 + 32 + kq*8);
  float rbv = rootb[d];
  #pragma unroll
  for (int t = 0; t < 4; ++t) {
    const float* sp = out + (size_t)(nb + t*16 + m15)*64 + kq*8;
    bf16x8 a0 = pack8v(*(const f32x4*)(sp),      *(const f32x4*)(sp + 4));
    bf16x8 a1 = pack8v(*(const f32x4*)(sp + 32), *(const f32x4*)(sp + 36));
    f32x4 p = __builtin_amdgcn_mfma_f32_16x16x32_bf16(a0, b0, zero4, 0, 0, 0);
    p = __builtin_amdgcn_mfma_f32_16x16x32_bf16(a1, b1, p, 0, 0, 0);
    #pragma unroll
    for (int r = 0; r < 4; ++r) {
      int ln = t*16 + kq*4 + r;
      int node = nb + ln;
      float mv = agg_c[node*64 + d] / fmaxf(cnt[node], 1.f) + rbv + p[r];
      agg_z[node*64 + d] = 0.f;     // re-zero for next layer's atomics
      m[node*64 + d] = mv;
      msh[ln*65 + d] = mv;
    }
  }
  __syncthreads();

  for (int c = tid; c < 1024; c += 256) {
    int n = c >> 4, g = c & 15;
    if (g < 10) {
      float lg = 0.f;
      #pragma unroll 8
      for (int k = 0; k < 64; ++k) lg += msh[n*65 + k] * gnlin[k*10 + g];
      lgsh[n*12 + g] = lg;
    }
  }
  __syncthreads();
  for (int c = tid; c < 1024; c += 256) {
    int n = c >> 4, g = c & 15;
    if (g < 10) {
      float mx = -1e30f;
      #pragma unroll
      for (int gg = 0; gg < 10; ++gg) mx = fmaxf(mx, lgsh[n*12 + gg]);
      float sum = 0.f;
      #pragma unroll
      for (int gg = 0; gg < 10; ++gg) sum += expf(lgsh[n*12 + gg] - mx);
      float sv = expf(lgsh[n*12 + g] - mx) / sum;
      sbuf[(nb + n)*16 + g] = sv;
      ssh[n*16 + g] = sv;
    }
  }
  __syncthreads();
  for (int c = tid; c < 640; c += 256) {
    int g = c >> 6, dd = c & 63;
    float a1 = 0.f, a2 = 0.f;
    #pragma unroll 8
    for (int n = 0; n < 64; ++n) {
      float t = ssh[n*16 + g] * msh[n*65 + dd];
      a1 += t; a2 += t*t;
    }
    atomicAdd(&stats[c], a1);
    atomicAdd(&stats[640 + c], a2);
  }
}

// ---------------- DGN-finalize + relu + GRU (MFMA) + residual (+ pooling on last) ----------------
__global__ __launch_bounds__(256) void k_gru(
    const float* __restrict__ m, const float* __restrict__ sbuf,
    const float* __restrict__ stats, const float* __restrict__ gamma,
    const float* __restrict__ beta, const short* __restrict__ gwihB,
    const short* __restrict__ gwhhB, const float* __restrict__ bih,
    const float* __restrict__ bhh, float* __restrict__ h,
    float* __restrict__ out, const int* __restrict__ batch,
    float* __restrict__ pooled, int do_pool) {
  __shared__ __align__(16) float mrsh[32*68];
  __shared__ float igsh[640];
  __shared__ float Bsh[64];
  __shared__ float ssh[512];
  const int tid = threadIdx.x, lane = tid & 63, wave = tid >> 6;
  const int m15 = lane & 15, kq = lane >> 4;
  const int nb = blockIdx.x * 32;
  const f32x4 zero4 = {0.f,0.f,0.f,0.f};
  const float invN = 1.f / (float)Nn;

  if (tid < 64) {
    float bacc = 0.f;
    #pragma unroll
    for (int g = 0; g < 10; ++g) {
      int c = g*64 + tid;
      float mu = stats[c] * invN;
      float var = stats[640 + c] * invN - mu*mu;
      float ig = (1.0f / sqrtf(var + EPSf)) * gamma[c];
      igsh[c] = ig;
      bacc += beta[c] - mu * ig;
    }
    Bsh[tid] = bacc;
  }
  if (tid < 512) ssh[tid] = sbuf[nb*16 + tid];
  __syncthreads();

  for (int idx = tid; idx < 2048; idx += 256) {
    int n = idx >> 6, dd = idx & 63;
    float mv = m[(nb + n)*64 + dd];
    float SA = 0.f;
    #pragma unroll
    for (int g = 0; g < 10; ++g) SA += ssh[n*16 + g] * igsh[g*64 + dd];
    mrsh[n*68 + dd] = fmaxf(mv * (1.f + LAMf*SA) + LAMf*Bsh[dd], 0.f);
  }
  __syncthreads();

  bf16x8 mrf[2][2], hf[2][2];
  #pragma unroll
  for (int t = 0; t < 2; ++t) {
    const float* mp = mrsh + (t*16 + m15)*68 + kq*8;
    const float* hp = h + (size_t)(nb + t*16 + m15)*64 + kq*8;
    #pragma unroll
    for (int ks = 0; ks < 2; ++ks) {
      mrf[t][ks] = pack8v(*(const f32x4*)(mp + ks*32), *(const f32x4*)(mp + ks*32 + 4));
      hf[t][ks]  = pack8v(*(const f32x4*)(hp + ks*32), *(const f32x4*)(hp + ks*32 + 4));
    }
  }
  const int d = wave*16 + m15;
  f32x4 gi[2][3], gh[2][3];
  #pragma unroll
  for (int p = 0; p < 3; ++p) {
    int j = p*64 + d;
    bf16x8 bi0 = *(const bf16x8*)(gwihB + j*64 + kq*8);
    bf16x8 bi1 = *(const bf16x8*)(gwihB + j*64 + 32 + kq*8);
    bf16x8 bh0 = *(const bf16x8*)(gwhhB + j*64 + kq*8);
    bf16x8 bh1 = *(const bf16x8*)(gwhhB + j*64 + 32 + kq*8);
    #pragma unroll
    for (int t = 0; t < 2; ++t) {
      f32x4 a = __builtin_amdgcn_mfma_f32_16x16x32_bf16(mrf[t][0], bi0, zero4, 0, 0, 0);
      gi[t][p] = __builtin_amdgcn_mfma_f32_16x16x32_bf16(mrf[t][1], bi1, a, 0, 0, 0);
      f32x4 b = __builtin_amdgcn_mfma_f32_16x16x32_bf16(hf[t][0], bh0, zero4, 0, 0, 0);
      gh[t][p] = __builtin_amdgcn_mfma_f32_16x16x32_bf16(hf[t][1], bh1, b, 0, 0, 0);
    }
  }
  float bir = bih[d],      bhr = bhh[d];
  float biz = bih[64 + d], bhz = bhh[64 + d];
  float bin = bih[128 + d], bhn = bhh[128 + d];
  __syncthreads();
  #pragma unroll
  for (int t = 0; t < 2; ++t) {
    #pragma unroll
    for (int r = 0; r < 4; ++r) {
      int node = nb + t*16 + kq*4 + r;
      float rr = sigm(gi[t][0][r] + bir + gh[t][0][r] + bhr);
      float z  = sigm(gi[t][1][r] + biz + gh[t][1][r] + bhz);
      float nn = tanhf(gi[t][2][r] + bin + rr * (gh[t][2][r] + bhn));
      float hv = h[node*64 + d];
      float hn = (1.f - z) * nn + z * hv;
      h[node*64 + d] = hn;
      float ov = hn + out[node*64 + d];
      out[node*64 + d] = ov;
      if (do_pool) atomicAdd(&pooled[batch[node]*64 + d], ov);
    }
  }
}

// ---------------- post FC + output ----------------
__global__ void k_final(const float* __restrict__ pooled, const float* __restrict__ pcnt,
                        const float* __restrict__ postW, const float* __restrict__ postb,
                        const float* __restrict__ outW, const float* __restrict__ outb,
                        float* __restrict__ y) {
  int b = blockIdx.x, d = threadIdx.x;
  __shared__ float pl[64];
  float c = fmaxf(pcnt[b], 1.f);
  pl[d] = pooled[b*64 + d] / c;
  __syncthreads();
  float acc = postb[d];
  #pragma unroll 8
  for (int k = 0; k < 64; ++k) acc += pl[k] * postW[k*64 + d];
  acc = fmaxf(acc, 0.f);
  float v = acc * outW[d];
  #pragma unroll
  for (int off = 32; off > 0; off >>= 1) v += __shfl_down(v, off, 64);
  if (d == 0) y[b] = v + outb[0];
}

extern "C" void kernel_launch(void* const* d_in, const int* in_sizes, int n_in,
                              void* d_out, int out_size, void* d_ws, size_t ws_size,
                              hipStream_t stream) {
  (void)in_sizes; (void)n_in; (void)out_size; (void)ws_size;
  const float* x        = (const float*)d_in[0];
  const float* edge_attr= (const float*)d_in[1];
  const float* preW     = (const float*)d_in[2];
  const float* preb     = (const float*)d_in[3];
  const float* ew1      = (const float*)d_in[4];
  const float* eb1      = (const float*)d_in[5];
  const float* ew2      = (const float*)d_in[6];
  const float* eb2      = (const float*)d_in[7];
  const float* rootw    = (const float*)d_in[8];
  const float* rootb    = (const float*)d_in[9];
  const float* gwih     = (const float*)d_in[10];
  const float* gwhh     = (const float*)d_in[11];
  const float* gbih     = (const float*)d_in[12];
  const float* gbhh     = (const float*)d_in[13];
  const float* gnlin    = (const float*)d_in[14];
  const float* gngamma  = (const float*)d_in[15];
  const float* gnbeta   = (const float*)d_in[16];
  const float* postW    = (const float*)d_in[17];
  const float* postb    = (const float*)d_in[18];
  const float* outW     = (const float*)d_in[19];
  const float* outb     = (const float*)d_in[20];
  const int*   eidx     = (const int*)d_in[21];
  const int*   batch    = (const int*)d_in[22];
  const int* src = eidx;
  const int* dst = eidx + Ee;
  float* y = (float*)d_out;

  float* ws     = (float*)d_ws;
  float* out    = ws;                     // N*64
  float* hbuf   = out    + Nn*64;         // N*64
  float* mbuf   = hbuf   + Nn*64;         // N*64
  float* sbuf   = mbuf   + Nn*64;         // N*16
  // ---- zeroed region (one memset): agg, stats x3, cnt, pooled, pcnt ----
  float* agg    = sbuf   + Nn*16;         // N*64
  float* stats  = agg    + Nn*64;         // 3*2048
  float* cnt    = stats  + 3*2048;        // N
  float* pooled = cnt    + Nn;            // 4096
  float* pcnt   = pooled + 4096;          // 64
  float* bfbase = pcnt   + 64;
  short* w1T    = (short*)bfbase;         // 3*4096
  short* b2T    = w1T    + 3*4096;        // 3*4096
  short* w2T    = b2T    + 3*4096;        // 3*262144
  short* rootwT = w2T    + 3*262144;      // 3*4096
  short* gwihB  = rootwT + 3*4096;        // 3*12288
  short* gwhhB  = gwihB  + 3*12288;       // 3*12288
  short* preWT  = gwhhB  + 3*12288;       // 8192

  size_t zfloats = (size_t)Nn*64 + 3*2048 + Nn + 4096 + 64;
  hipMemsetAsync(agg, 0, zfloats*sizeof(float), stream);

  k_setup<<<329, 256, 0, stream>>>(ew1, ew2, eb2, rootw, gwih, gwhh, preW,
                                   preb, postW, postb, outW, outb,
                                   dst, batch,
                                   w1T, b2T, w2T, rootwT, gwihB, gwhhB, preWT,
                                   cnt, pcnt, y);
  k_pre<<<Nn/32, 256, 0, stream>>>(x, preWT, preb, out, hbuf);

  for (int i = 0; i < 3; ++i) {
    k_msg<<<Ee/64, 512, 0, stream>>>(out, edge_attr,
                                     w1T + i*4096, eb1 + i*64,
                                     w2T + i*262144, b2T + i*4096,
                                     src, dst, agg);
    k_m_fused<<<Nn/64, 256, 0, stream>>>(agg, cnt, out, rootwT + i*4096,
                                         rootb + i*64, gnlin + i*640, mbuf, sbuf,
                                         stats + i*2048, agg);
    k_gru<<<Nn/32, 256, 0, stream>>>(mbuf, sbuf, stats + i*2048,
                                     gngamma + i*640, gnbeta + i*640,
                                     gwihB + i*12288, gwhhB + i*12288,
                                     gbih + i*192, gbhh + i*192, hbuf, out,
                                     batch, pooled, (i == 2) ? 1 : 0);
  }

  k_final<<<Bb, 64, 0, stream>>>(pooled, pcnt, postW, postb, outW, outb, y);
}

// Round 5
// 428.457 us; speedup vs baseline: 1.2115x; 1.2115x over previous
//
#include <hip/hip_runtime.h>
#include <math.h>

#define Nn 4096
#define Ee 32768
#define Bb 64
#define FINc 128
#define Dd 64
#define SIGf 0.15f
#define LAMf 0.01f
#define EPSf 1e-5f

typedef __attribute__((ext_vector_type(8))) short bf16x8;
typedef __attribute__((ext_vector_type(4))) float f32x4;

__device__ inline short f2bf(float f) {
  union { float f; unsigned u; } v; v.f = f;
  unsigned r = v.u + 0x7fffu + ((v.u >> 16) & 1u);
  return (short)(r >> 16);
}
__device__ inline bf16x8 pack8v(f32x4 a, f32x4 b) {
  bf16x8 r;
  r[0]=f2bf(a.x); r[1]=f2bf(a.y); r[2]=f2bf(a.z); r[3]=f2bf(a.w);
  r[4]=f2bf(b.x); r[5]=f2bf(b.y); r[6]=f2bf(b.z); r[7]=f2bf(b.w);
  return r;
}
__device__ inline float sigm(float x) { return 1.f / (1.f + expf(-x)); }

// ================= setup: w2 transpose + packs + count + pcnt + tkl =================
__global__ __launch_bounds__(256) void k_setup(
    const float* __restrict__ w1, const float* __restrict__ w2,
    const float* __restrict__ b2, const float* __restrict__ rootw,
    const float* __restrict__ gwih, const float* __restrict__ gwhh,
    const float* __restrict__ preW,
    const float* __restrict__ preb, const float* __restrict__ postW,
    const float* __restrict__ postb, const float* __restrict__ outW,
    const float* __restrict__ outb,
    const int* __restrict__ dst, const int* __restrict__ batch,
    short* __restrict__ w1T, short* __restrict__ b2T,
    short* __restrict__ w2T, short* __restrict__ rootwT,
    short* __restrict__ gwihB, short* __restrict__ gwhhB,
    short* __restrict__ preWT,
    float* __restrict__ cnt, float* __restrict__ pcnt, float* __restrict__ y) {
  const int b = blockIdx.x, tid = threadIdx.x;
  if (b < 192) {
    __shared__ float tile[64*65];
    const int l = b >> 6, h = b & 63;
    const float* srcp = w2 + (size_t)(l*64 + h)*4096;
    #pragma unroll
    for (int it = 0; it < 16; ++it) {
      int j = tid + 256*it;                 // j = f*64 + o, coalesced read
      tile[(j >> 6)*65 + (j & 63)] = srcp[j];
    }
    __syncthreads();
    short* dstp = w2T + (size_t)(l*64 + h)*4096;
    #pragma unroll
    for (int it = 0; it < 16; ++it) {
      int j = tid + 256*it;                 // j = o*64 + f, coalesced write
      int o = j >> 6, f = j & 63;
      dstp[j] = f2bf(tile[f*65 + o]);
    }
  } else if (b < 200) {
    int base = (b - 192)*256 + tid;         // 0..2047
    for (int idx = base; idx < 12288; idx += 2048) {
      int l = idx >> 12, r = idx & 4095;
      int f = r & 63, c = r >> 6;
      w1T[idx]    = f2bf(w1[l*4096 + f*64 + c]);
      b2T[idx]    = f2bf(b2[l*4096 + f*64 + c]);
      rootwT[idx] = f2bf(rootw[l*4096 + f*64 + c]);
    }
    for (int idx = base; idx < 36864; idx += 2048) {
      gwihB[idx] = f2bf(gwih[idx]);
      gwhhB[idx] = f2bf(gwhh[idx]);
    }
    for (int idx = base; idx < 8192; idx += 2048) {
      int k = idx & 127, d = idx >> 7;
      preWT[idx] = f2bf(preW[k*64 + d]);
    }
  } else if (b < 328) {
    int e = (b - 200)*256 + tid;
    atomicAdd(&cnt[dst[e]], 1.0f);
    if (e < Nn) atomicAdd(&pcnt[batch[e]], 1.0f);
  } else {
    const float logc = logf(SIGf * sqrtf(6.28318530717958647692f));
    const float c2 = 0.5f / (SIGf * SIGf);
    float acc = 0.f;
    for (int i = tid; i < FINc*Dd; i += 256) { float w = preW[i];  acc += c2*w*w + logc; }
    for (int i = tid; i < Dd; i += 256)      { float w = preb[i];  acc += c2*w*w + logc; }
    for (int i = tid; i < Dd*Dd; i += 256)   { float w = postW[i]; acc += c2*w*w + logc; }
    for (int i = tid; i < Dd; i += 256)      { float w = postb[i]; acc += c2*w*w + logc; }
    for (int i = tid; i < Dd; i += 256)      { float w = outW[i];  acc += c2*w*w + logc; }
    if (tid == 0)                            { float w = outb[0];  acc += c2*w*w + logc; }
    __shared__ float red[256];
    red[tid] = acc; __syncthreads();
    for (int s = 128; s > 0; s >>= 1) { if (tid < s) red[tid] += red[tid+s]; __syncthreads(); }
    if (tid == 0) y[Bb] = red[0];
  }
}

// ---------------- pre FC + relu via MFMA ----------------
__global__ __launch_bounds__(256) void k_pre(const float* __restrict__ x,
                                             const short* __restrict__ preWT,
                                             const float* __restrict__ preb,
                                             float* __restrict__ out, float* __restrict__ h) {
  const int tid = threadIdx.x, lane = tid & 63, wave = tid >> 6;
  const int m15 = lane & 15, kq = lane >> 4;
  const int nb = blockIdx.x * 32;
  const f32x4 zero4 = {0.f,0.f,0.f,0.f};
  const int d = wave*16 + m15;
  bf16x8 bfr[4];
  #pragma unroll
  for (int c = 0; c < 4; ++c)
    bfr[c] = *(const bf16x8*)(preWT + d*128 + c*32 + kq*8);
  #pragma unroll
  for (int t = 0; t < 2; ++t) {
    const float* xp = x + (size_t)(nb + t*16 + m15)*128 + kq*8;
    f32x4 p = zero4;
    #pragma unroll
    for (int c = 0; c < 4; ++c) {
      bf16x8 a = pack8v(*(const f32x4*)(xp + c*32), *(const f32x4*)(xp + c*32 + 4));
      p = __builtin_amdgcn_mfma_f32_16x16x32_bf16(a, bfr[c], p, 0, 0, 0);
    }
    float bv = preb[d];
    #pragma unroll
    for (int r = 0; r < 4; ++r) {
      int node = nb + t*16 + kq*4 + r;
      float v = fmaxf(p[r] + bv, 0.f);
      out[node*64 + d] = v;
      h[node*64 + d] = v;
    }
  }
}

// ====== fused edge-MLP + bilinear message GEMM (round-3 structure, M=32 tiles) ======
// 256 threads / 4 waves; wave owns o-group = wave*16+m15; grid Ee/32 for 16 waves/CU.
__global__ __launch_bounds__(256) void k_msg(
    const float* __restrict__ out, const float* __restrict__ edge_attr,
    const short* __restrict__ w1T, const float* __restrict__ b1,
    const short* __restrict__ w2T, const short* __restrict__ b2T,
    const int* __restrict__ src, const int* __restrict__ dst,
    float* __restrict__ agg) {
  __shared__ __align__(16) float hidT[64*36];   // [h][e], stride 36 dwords (16B-aligned rows)
  __shared__ int srcv[32];
  __shared__ int dstv[32];

  const int tid  = threadIdx.x;
  const int lane = tid & 63;
  const int wave = tid >> 6;      // o-group
  const int m15  = lane & 15;
  const int kq   = lane >> 4;
  const int ebase = blockIdx.x * 32;

  if (tid < 32) { srcv[tid] = src[ebase + tid]; dstv[tid] = dst[ebase + tid]; }
  __syncthreads();

  const f32x4 zero4 = {0.f, 0.f, 0.f, 0.f};

  // ---- A-fragments: s = out[src] for the 32 edges (kept in regs all K-loop) ----
  bf16x8 sfrag[2][2];
  #pragma unroll
  for (int t = 0; t < 2; ++t) {
    int node = srcv[t*16 + m15];
    const float* sp = out + (size_t)node*64 + kq*8;
    #pragma unroll
    for (int ks = 0; ks < 2; ++ks)
      sfrag[t][ks] = pack8v(*(const f32x4*)(sp + ks*32), *(const f32x4*)(sp + ks*32 + 4));
  }

  // ---- hid = relu(ea @ w1 + b1) via MFMA; wave computes its 16 h-cols for both tiles ----
  {
    const short* wp = w1T + (wave*16 + m15)*64 + kq*8;
    bf16x8 bw0 = *(const bf16x8*)(wp);
    bf16x8 bw1 = *(const bf16x8*)(wp + 32);
    float b1v = b1[wave*16 + m15];
    #pragma unroll
    for (int t = 0; t < 2; ++t) {
      const float* ep = edge_attr + (size_t)(ebase + t*16 + m15)*64 + kq*8;
      bf16x8 a0 = pack8v(*(const f32x4*)(ep),      *(const f32x4*)(ep + 4));
      bf16x8 a1 = pack8v(*(const f32x4*)(ep + 32), *(const f32x4*)(ep + 36));
      f32x4 p = __builtin_amdgcn_mfma_f32_16x16x32_bf16(a0, bw0, zero4, 0, 0, 0);
      p = __builtin_amdgcn_mfma_f32_16x16x32_bf16(a1, bw1, p, 0, 0, 0);
      f32x4 v;
      v.x = fmaxf(p.x + b1v, 0.f); v.y = fmaxf(p.y + b1v, 0.f);
      v.z = fmaxf(p.z + b1v, 0.f); v.w = fmaxf(p.w + b1v, 0.f);
      *(f32x4*)(hidT + (wave*16 + m15)*36 + t*16 + kq*4) = v;
    }
  }
  __syncthreads();

  // ---- K-loop over 64 h-chunks (round-3 1-ahead prefetch) ----
  f32x4 acc[2] = {zero4, zero4};
  const short* w2base = w2T + (wave*16 + m15)*64 + kq*8;
  const short* b2p    = b2T + (wave*16 + m15)*64 + kq*8;
  bf16x8 bc0 = *(const bf16x8*)(w2base);
  bf16x8 bc1 = *(const bf16x8*)(w2base + 32);
  for (int h = 0; h < 64; ++h) {
    const short* nb = (h < 63) ? (w2base + (size_t)(h + 1)*4096) : b2p;
    bf16x8 pb0 = *(const bf16x8*)(nb);
    bf16x8 pb1 = *(const bf16x8*)(nb + 32);
    #pragma unroll
    for (int t = 0; t < 2; ++t) {
      f32x4 p = __builtin_amdgcn_mfma_f32_16x16x32_bf16(sfrag[t][0], bc0, zero4, 0, 0, 0);
      p = __builtin_amdgcn_mfma_f32_16x16x32_bf16(sfrag[t][1], bc1, p, 0, 0, 0);
      f32x4 hv = *(const f32x4*)(hidT + h*36 + t*16 + kq*4);
      acc[t].x += hv.x * p.x; acc[t].y += hv.y * p.y;
      acc[t].z += hv.z * p.z; acc[t].w += hv.w * p.w;
    }
    bc0 = pb0; bc1 = pb1;
  }
  // b2 term (scale 1)
  #pragma unroll
  for (int t = 0; t < 2; ++t) {
    f32x4 p = __builtin_amdgcn_mfma_f32_16x16x32_bf16(sfrag[t][0], bc0, zero4, 0, 0, 0);
    p = __builtin_amdgcn_mfma_f32_16x16x32_bf16(sfrag[t][1], bc1, p, 0, 0, 0);
    acc[t].x += p.x; acc[t].y += p.y; acc[t].z += p.z; acc[t].w += p.w;
  }

  // ---- scatter-add ----
  const int o = wave*16 + m15;
  #pragma unroll
  for (int t = 0; t < 2; ++t) {
    #pragma unroll
    for (int r = 0; r < 4; ++r) {
      int e = t*16 + kq*4 + r;
      atomicAdd(&agg[(size_t)dstv[e]*64 + o], acc[t][r]);
    }
  }
}

// ---------------- fused: m = agg/cnt + out@rootw + rootb ; softmax ; BN stats ----------------
__global__ __launch_bounds__(256) void k_m_fused(
    const float* __restrict__ agg_c, const float* __restrict__ cnt,
    const float* __restrict__ out, const short* __restrict__ rootwT,
    const float* __restrict__ rootb, const float* __restrict__ gnlin,
    float* __restrict__ m, float* __restrict__ sbuf, float* __restrict__ stats,
    float* __restrict__ agg_z) {
  __shared__ float msh[64*65];
  __shared__ float lgsh[64*12];
  __shared__ float ssh[64*16];
  const int tid = threadIdx.x, lane = tid & 63, wave = tid >> 6;
  const int m15 = lane & 15, kq = lane >> 4;
  const int nb = blockIdx.x * 64;
  const f32x4 zero4 = {0.f,0.f,0.f,0.f};
  const int d = wave*16 + m15;

  bf16x8 b0 = *(const bf16x8*)(rootwT + d*64 + kq*8);
  bf16x8 b1 = *(const bf16x8*)(rootwT + d*64 + 32 + kq*8);
  float rbv = rootb[d];
  #pragma unroll
  for (int t = 0; t < 4; ++t) {
    const float* sp = out + (size_t)(nb + t*16 + m15)*64 + kq*8;
    bf16x8 a0 = pack8v(*(const f32x4*)(sp),      *(const f32x4*)(sp + 4));
    bf16x8 a1 = pack8v(*(const f32x4*)(sp + 32), *(const f32x4*)(sp + 36));
    f32x4 p = __builtin_amdgcn_mfma_f32_16x16x32_bf16(a0, b0, zero4, 0, 0, 0);
    p = __builtin_amdgcn_mfma_f32_16x16x32_bf16(a1, b1, p, 0, 0, 0);
    #pragma unroll
    for (int r = 0; r < 4; ++r) {
      int ln = t*16 + kq*4 + r;
      int node = nb + ln;
      float mv = agg_c[node*64 + d] / fmaxf(cnt[node], 1.f) + rbv + p[r];
      agg_z[node*64 + d] = 0.f;     // re-zero for next layer's atomics
      m[node*64 + d] = mv;
      msh[ln*65 + d] = mv;
    }
  }
  __syncthreads();

  for (int c = tid; c < 1024; c += 256) {
    int n = c >> 4, g = c & 15;
    if (g < 10) {
      float lg = 0.f;
      #pragma unroll 8
      for (int k = 0; k < 64; ++k) lg += msh[n*65 + k] * gnlin[k*10 + g];
      lgsh[n*12 + g] = lg;
    }
  }
  __syncthreads();
  for (int c = tid; c < 1024; c += 256) {
    int n = c >> 4, g = c & 15;
    if (g < 10) {
      float mx = -1e30f;
      #pragma unroll
      for (int gg = 0; gg < 10; ++gg) mx = fmaxf(mx, lgsh[n*12 + gg]);
      float sum = 0.f;
      #pragma unroll
      for (int gg = 0; gg < 10; ++gg) sum += expf(lgsh[n*12 + gg] - mx);
      float sv = expf(lgsh[n*12 + g] - mx) / sum;
      sbuf[(nb + n)*16 + g] = sv;
      ssh[n*16 + g] = sv;
    }
  }
  __syncthreads();
  for (int c = tid; c < 640; c += 256) {
    int g = c >> 6, dd = c & 63;
    float a1 = 0.f, a2 = 0.f;
    #pragma unroll 8
    for (int n = 0; n < 64; ++n) {
      float t = ssh[n*16 + g] * msh[n*65 + dd];
      a1 += t; a2 += t*t;
    }
    atomicAdd(&stats[c], a1);
    atomicAdd(&stats[640 + c], a2);
  }
}

// ---------------- DGN-finalize + relu + GRU (MFMA) + residual (+ pooling on last) ----------------
__global__ __launch_bounds__(256) void k_gru(
    const float* __restrict__ m, const float* __restrict__ sbuf,
    const float* __restrict__ stats, const float* __restrict__ gamma,
    const float* __restrict__ beta, const short* __restrict__ gwihB,
    const short* __restrict__ gwhhB, const float* __restrict__ bih,
    const float* __restrict__ bhh, float* __restrict__ h,
    float* __restrict__ out, const int* __restrict__ batch,
    float* __restrict__ pooled, int do_pool) {
  __shared__ __align__(16) float mrsh[32*68];
  __shared__ float igsh[640];
  __shared__ float Bsh[64];
  __shared__ float ssh[512];
  const int tid = threadIdx.x, lane = tid & 63, wave = tid >> 6;
  const int m15 = lane & 15, kq = lane >> 4;
  const int nb = blockIdx.x * 32;
  const f32x4 zero4 = {0.f,0.f,0.f,0.f};
  const float invN = 1.f / (float)Nn;

  if (tid < 64) {
    float bacc = 0.f;
    #pragma unroll
    for (int g = 0; g < 10; ++g) {
      int c = g*64 + tid;
      float mu = stats[c] * invN;
      float var = stats[640 + c] * invN - mu*mu;
      float ig = (1.0f / sqrtf(var + EPSf)) * gamma[c];
      igsh[c] = ig;
      bacc += beta[c] - mu * ig;
    }
    Bsh[tid] = bacc;
  }
  if (tid < 512) ssh[tid] = sbuf[nb*16 + tid];
  __syncthreads();

  for (int idx = tid; idx < 2048; idx += 256) {
    int n = idx >> 6, dd = idx & 63;
    float mv = m[(nb + n)*64 + dd];
    float SA = 0.f;
    #pragma unroll
    for (int g = 0; g < 10; ++g) SA += ssh[n*16 + g] * igsh[g*64 + dd];
    mrsh[n*68 + dd] = fmaxf(mv * (1.f + LAMf*SA) + LAMf*Bsh[dd], 0.f);
  }
  __syncthreads();

  bf16x8 mrf[2][2], hf[2][2];
  #pragma unroll
  for (int t = 0; t < 2; ++t) {
    const float* mp = mrsh + (t*16 + m15)*68 + kq*8;
    const float* hp = h + (size_t)(nb + t*16 + m15)*64 + kq*8;
    #pragma unroll
    for (int ks = 0; ks < 2; ++ks) {
      mrf[t][ks] = pack8v(*(const f32x4*)(mp + ks*32), *(const f32x4*)(mp + ks*32 + 4));
      hf[t][ks]  = pack8v(*(const f32x4*)(hp + ks*32), *(const f32x4*)(hp + ks*32 + 4));
    }
  }
  const int d = wave*16 + m15;
  f32x4 gi[2][3], gh[2][3];
  #pragma unroll
  for (int p = 0; p < 3; ++p) {
    int j = p*64 + d;
    bf16x8 bi0 = *(const bf16x8*)(gwihB + j*64 + kq*8);
    bf16x8 bi1 = *(const bf16x8*)(gwihB + j*64 + 32 + kq*8);
    bf16x8 bh0 = *(const bf16x8*)(gwhhB + j*64 + kq*8);
    bf16x8 bh1 = *(const bf16x8*)(gwhhB + j*64 + 32 + kq*8);
    #pragma unroll
    for (int t = 0; t < 2; ++t) {
      f32x4 a = __builtin_amdgcn_mfma_f32_16x16x32_bf16(mrf[t][0], bi0, zero4, 0, 0, 0);
      gi[t][p] = __builtin_amdgcn_mfma_f32_16x16x32_bf16(mrf[t][1], bi1, a, 0, 0, 0);
      f32x4 b = __builtin_amdgcn_mfma_f32_16x16x32_bf16(hf[t][0], bh0, zero4, 0, 0, 0);
      gh[t][p] = __builtin_amdgcn_mfma_f32_16x16x32_bf16(hf[t][1], bh1, b, 0, 0, 0);
    }
  }
  float bir = bih[d],      bhr = bhh[d];
  float biz = bih[64 + d], bhz = bhh[64 + d];
  float bin = bih[128 + d], bhn = bhh[128 + d];
  __syncthreads();
  #pragma unroll
  for (int t = 0; t < 2; ++t) {
    #pragma unroll
    for (int r = 0; r < 4; ++r) {
      int node = nb + t*16 + kq*4 + r;
      float rr = sigm(gi[t][0][r] + bir + gh[t][0][r] + bhr);
      float z  = sigm(gi[t][1][r] + biz + gh[t][1][r] + bhz);
      float nn = tanhf(gi[t][2][r] + bin + rr * (gh[t][2][r] + bhn));
      float hv = h[node*64 + d];
      float hn = (1.f - z) * nn + z * hv;
      h[node*64 + d] = hn;
      float ov = hn + out[node*64 + d];
      out[node*64 + d] = ov;
      if (do_pool) atomicAdd(&pooled[batch[node]*64 + d], ov);
    }
  }
}

// ---------------- post FC + output ----------------
__global__ void k_final(const float* __restrict__ pooled, const float* __restrict__ pcnt,
                        const float* __restrict__ postW, const float* __restrict__ postb,
                        const float* __restrict__ outW, const float* __restrict__ outb,
                        float* __restrict__ y) {
  int b = blockIdx.x, d = threadIdx.x;
  __shared__ float pl[64];
  float c = fmaxf(pcnt[b], 1.f);
  pl[d] = pooled[b*64 + d] / c;
  __syncthreads();
  float acc = postb[d];
  #pragma unroll 8
  for (int k = 0; k < 64; ++k) acc += pl[k] * postW[k*64 + d];
  acc = fmaxf(acc, 0.f);
  float v = acc * outW[d];
  #pragma unroll
  for (int off = 32; off > 0; off >>= 1) v += __shfl_down(v, off, 64);
  if (d == 0) y[b] = v + outb[0];
}

extern "C" void kernel_launch(void* const* d_in, const int* in_sizes, int n_in,
                              void* d_out, int out_size, void* d_ws, size_t ws_size,
                              hipStream_t stream) {
  (void)in_sizes; (void)n_in; (void)out_size; (void)ws_size;
  const float* x        = (const float*)d_in[0];
  const float* edge_attr= (const float*)d_in[1];
  const float* preW     = (const float*)d_in[2];
  const float* preb     = (const float*)d_in[3];
  const float* ew1      = (const float*)d_in[4];
  const float* eb1      = (const float*)d_in[5];
  const float* ew2      = (const float*)d_in[6];
  const float* eb2      = (const float*)d_in[7];
  const float* rootw    = (const float*)d_in[8];
  const float* rootb    = (const float*)d_in[9];
  const float* gwih     = (const float*)d_in[10];
  const float* gwhh     = (const float*)d_in[11];
  const float* gbih     = (const float*)d_in[12];
  const float* gbhh     = (const float*)d_in[13];
  const float* gnlin    = (const float*)d_in[14];
  const float* gngamma  = (const float*)d_in[15];
  const float* gnbeta   = (const float*)d_in[16];
  const float* postW    = (const float*)d_in[17];
  const float* postb    = (const float*)d_in[18];
  const float* outW     = (const float*)d_in[19];
  const float* outb     = (const float*)d_in[20];
  const int*   eidx     = (const int*)d_in[21];
  const int*   batch    = (const int*)d_in[22];
  const int* src = eidx;
  const int* dst = eidx + Ee;
  float* y = (float*)d_out;

  float* ws     = (float*)d_ws;
  float* out    = ws;                     // N*64
  float* hbuf   = out    + Nn*64;         // N*64
  float* mbuf   = hbuf   + Nn*64;         // N*64
  float* sbuf   = mbuf   + Nn*64;         // N*16
  // ---- zeroed region (one memset): agg, stats x3, cnt, pooled, pcnt ----
  float* agg    = sbuf   + Nn*16;         // N*64
  float* stats  = agg    + Nn*64;         // 3*2048
  float* cnt    = stats  + 3*2048;        // N
  float* pooled = cnt    + Nn;            // 4096
  float* pcnt   = pooled + 4096;          // 64
  float* bfbase = pcnt   + 64;
  short* w1T    = (short*)bfbase;         // 3*4096
  short* b2T    = w1T    + 3*4096;        // 3*4096
  short* w2T    = b2T    + 3*4096;        // 3*262144
  short* rootwT = w2T    + 3*262144;      // 3*4096
  short* gwihB  = rootwT + 3*4096;        // 3*12288
  short* gwhhB  = gwihB  + 3*12288;       // 3*12288
  short* preWT  = gwhhB  + 3*12288;       // 8192

  size_t zfloats = (size_t)Nn*64 + 3*2048 + Nn + 4096 + 64;
  hipMemsetAsync(agg, 0, zfloats*sizeof(float), stream);

  k_setup<<<329, 256, 0, stream>>>(ew1, ew2, eb2, rootw, gwih, gwhh, preW,
                                   preb, postW, postb, outW, outb,
                                   dst, batch,
                                   w1T, b2T, w2T, rootwT, gwihB, gwhhB, preWT,
                                   cnt, pcnt, y);
  k_pre<<<Nn/32, 256, 0, stream>>>(x, preWT, preb, out, hbuf);

  for (int i = 0; i < 3; ++i) {
    k_msg<<<Ee/32, 256, 0, stream>>>(out, edge_attr,
                                     w1T + i*4096, eb1 + i*64,
                                     w2T + i*262144, b2T + i*4096,
                                     src, dst, agg);
    k_m_fused<<<Nn/64, 256, 0, stream>>>(agg, cnt, out, rootwT + i*4096,
                                         rootb + i*64, gnlin + i*640, mbuf, sbuf,
                                         stats + i*2048, agg);
    k_gru<<<Nn/32, 256, 0, stream>>>(mbuf, sbuf, stats + i*2048,
                                     gngamma + i*640, gnbeta + i*640,
                                     gwihB + i*12288, gwhhB + i*12288,
                                     gbih + i*192, gbhh + i*192, hbuf, out,
                                     batch, pooled, (i == 2) ? 1 : 0);
  }

  k_final<<<Bb, 64, 0, stream>>>(pooled, pcnt, postW, postb, outW, outb, y);
}